// Round 9
// baseline (8337.099 us; speedup 1.0000x reference)
//
#include <hip/hip_runtime.h>

// ---------------------------------------------------------------------------
// FastCASSBlock: LN -> gradient-direction selector -> biGRU (input-proj fused
// into scan chunks) -> out_proj + residual.
// v9 = v8 with the compile fix: no asm pins on indexed array elements (the
// AMDGPU backend rejects tied indirect register operands). Laundered base
// pointer only; wq[32] is statically indexed + fully unrolled -> registers.
// Recurrence matvec on VALU v_dot2_f32_f16 (dense), chunk input-proj GEMM on
// the MFMA pipe; h broadcast via same-address LDS uint4 reads.
// Workspace layout (bytes), total ~98 MiB:
//   xn    f16 [65536,256]  @ 0           (33554432)
//   gray  f32 [65536]      @ 33554432    (262144)
//   flag  i32 [16]         @ 33816576    (256)
//   whh16 f16 [2][768,256] @ 33816832    (786432)   plain rows, dirs stacked
//   out_w f16 [256,512]    @ 34603264    (262144)
//   wcomb f16 [1536,256]   @ 34865408    (786432)
//   badj  f32 [1536]       @ 35651840    (6144)     bcomb + bhh folded (r,z)
//   ycat  f16 [65536,512]  @ 35658240    (67108864)
// ---------------------------------------------------------------------------

#define L_   4096
#define CH   32     // scan chunk length (steps)
#define NCH  128    // L_/CH

typedef __attribute__((ext_vector_type(8))) _Float16 half8;
typedef __attribute__((ext_vector_type(2))) _Float16 half2v;
typedef __attribute__((ext_vector_type(4))) float f32x4;

__device__ __forceinline__ unsigned short f2h(float f) {
  _Float16 h = (_Float16)f;
  return __builtin_bit_cast(unsigned short, h);
}
__device__ __forceinline__ float h2f(unsigned short u) {
  return (float)__builtin_bit_cast(_Float16, u);
}
__device__ __forceinline__ float sigm(float x) {
  return __builtin_amdgcn_rcpf(1.f + __expf(-x));
}
__device__ __forceinline__ float tanhf_(float x) {
  return 1.f - 2.f * __builtin_amdgcn_rcpf(1.f + __expf(2.f * x));
}
__device__ __forceinline__ float dot2(unsigned w, unsigned h, float c) {
  return __builtin_amdgcn_fdot2(__builtin_bit_cast(half2v, w),
                                __builtin_bit_cast(half2v, h), c, false);
}

// --------------------------- f32 -> f16 convert ----------------------------
__global__ __launch_bounds__(256) void k_f2h(const float* __restrict__ in,
                                             unsigned short* __restrict__ out,
                                             int n) {
  int i = blockIdx.x * 256 + threadIdx.x;
  if (i < n) out[i] = f2h(in[i]);
}

// ------------------- wcomb[n,c] = sum_j wih[n,j]*in_w[j,c] -----------------
__global__ __launch_bounds__(256) void k_wcomb(const float* __restrict__ wih_f,
                                               const float* __restrict__ wih_b,
                                               const float* __restrict__ in_w,
                                               unsigned short* __restrict__ wcomb) {
  const int n = blockIdx.x;  // 0..1535
  const float* wrow = (n < 768) ? (wih_f + (long)n * 512)
                                : (wih_b + (long)(n - 768) * 512);
  const int k = threadIdx.x;  // 0..255
  float acc = 0.f;
  for (int j = 0; j < 512; ++j) acc += wrow[j] * in_w[j * 256 + k];
  wcomb[(long)n * 256 + k] = f2h(acc);
}

// -- badj[n] = bih[n] + sum_j wih[n,j]*in_b[j] (+ bhh[n] for r/z slots) ------
__global__ __launch_bounds__(256) void k_bcomb(const float* __restrict__ wih_f,
                                               const float* __restrict__ wih_b,
                                               const float* __restrict__ in_b,
                                               const float* __restrict__ bih_f,
                                               const float* __restrict__ bih_b,
                                               const float* __restrict__ bhh_f,
                                               const float* __restrict__ bhh_b,
                                               float* __restrict__ badj) {
  int n = blockIdx.x * 256 + threadIdx.x;
  if (n >= 1536) return;
  const int dir = n >= 768;
  const int g = dir ? (n - 768) : n;
  const float* wrow = (dir ? wih_b : wih_f) + (long)g * 512;
  float acc = (dir ? bih_b : bih_f)[g];
  for (int j = 0; j < 512; ++j) acc += wrow[j] * in_b[j];
  if (g < 512) acc += (dir ? bhh_b : bhh_f)[g];  // fold bhh for r,z gates
  badj[n] = acc;
}

// --------------------------- LayerNorm + gray ------------------------------
__global__ __launch_bounds__(256) void k_ln(const float* __restrict__ x,
                                            const float* __restrict__ gamma,
                                            const float* __restrict__ beta,
                                            unsigned short* __restrict__ xn,
                                            float* __restrict__ gray) {
  const int lane = threadIdx.x & 63;
  const long pix = (long)blockIdx.x * 4 + (threadIdx.x >> 6);
  const float4 v = *(const float4*)(x + pix * 256 + lane * 4);
  float s = v.x + v.y + v.z + v.w;
  float s2 = v.x * v.x + v.y * v.y + v.z * v.z + v.w * v.w;
#pragma unroll
  for (int off = 32; off > 0; off >>= 1) {
    s += __shfl_xor(s, off, 64);
    s2 += __shfl_xor(s2, off, 64);
  }
  const float mu = s * (1.f / 256.f);
  const float var = fmaxf(s2 * (1.f / 256.f) - mu * mu, 0.f);
  const float rstd = rsqrtf(var + 1e-5f);
  const float4 gm = *(const float4*)(gamma + lane * 4);
  const float4 bt = *(const float4*)(beta + lane * 4);
  float o0 = (v.x - mu) * rstd * gm.x + bt.x;
  float o1 = (v.y - mu) * rstd * gm.y + bt.y;
  float o2 = (v.z - mu) * rstd * gm.z + bt.z;
  float o3 = (v.w - mu) * rstd * gm.w + bt.w;
  ushort4 o;
  o.x = f2h(o0); o.y = f2h(o1); o.z = f2h(o2); o.w = f2h(o3);
  *(ushort4*)(xn + pix * 256 + lane * 4) = o;
  float gs = o0 + o1 + o2 + o3;
#pragma unroll
  for (int off = 32; off > 0; off >>= 1) gs += __shfl_xor(gs, off, 64);
  if (lane == 0) gray[pix] = gs * (1.f / 256.f);
}

// --------------------- gradient-direction selector -------------------------
__device__ __forceinline__ int refl64(int m) {
  return m < 0 ? -m : (m > 63 ? 126 - m : m);
}

__global__ __launch_bounds__(256) void k_sel(const float* __restrict__ gray,
                                             const float* __restrict__ w1,
                                             const float* __restrict__ b1,
                                             const float* __restrict__ w2,
                                             const float* __restrict__ b2,
                                             int* __restrict__ flag) {
  __shared__ float g[64][65];
  __shared__ float part[4][4];
  const int b = blockIdx.x;
  const int tid = threadIdx.x;
  for (int r = 0; r < 16; ++r) {
    int p = tid + 256 * r;
    g[p >> 6][p & 63] = gray[(long)b * 4096 + p];
  }
  __syncthreads();
  const float S = 66.f / 64.f;
  float sh = 0.f, sv = 0.f, sd = 0.f, sa = 0.f;
  for (int rr = 0; rr < 16; ++rr) {
    int p = tid + 256 * rr;
    int h = p >> 6, w = p & 63;
    float srci = (h + 0.5f) * S - 0.5f;
    int i0 = (int)srci;
    float ai = srci - (float)i0;
    int i1 = i0 + 1; if (i1 > 65) i1 = 65;
    int r0 = refl64(i0 - 1), r1 = refl64(i1 - 1);
    int wl = w ? (w - 1) : 1;
    int wr2 = (w == 63) ? 62 : (w + 1);
    float GH0 = fabsf(g[r0][wr2] - g[r0][wl]);
    float GH1 = fabsf(g[r1][wr2] - g[r1][wl]);
    float ghr = GH0 + ai * (GH1 - GH0);
    float srcj = (w + 0.5f) * S - 0.5f;
    int j0 = (int)srcj;
    float aj = srcj - (float)j0;
    int j1 = j0 + 1; if (j1 > 65) j1 = 65;
    int c0 = refl64(j0 - 1), c1 = refl64(j1 - 1);
    int hu = h ? (h - 1) : 1;
    int hd = (h == 63) ? 62 : (h + 1);
    float GV0 = fabsf(g[hd][c0] - g[hu][c0]);
    float GV1 = fabsf(g[hd][c1] - g[hu][c1]);
    float gvr = GV0 + aj * (GV1 - GV0);
    float wt = ((h == 0 || h == 63) ? 2.f : 3.f) *
               ((w == 0 || w == 63) ? 2.f : 3.f);
    sh += wt * ghr;
    sv += wt * gvr;
    sd += wt * 0.5f * (ghr + gvr);
    sa += wt * fabsf(ghr - gvr);
  }
#pragma unroll
  for (int off = 32; off > 0; off >>= 1) {
    sh += __shfl_xor(sh, off, 64);
    sv += __shfl_xor(sv, off, 64);
    sd += __shfl_xor(sd, off, 64);
    sa += __shfl_xor(sa, off, 64);
  }
  if ((tid & 63) == 0) {
    part[tid >> 6][0] = sh; part[tid >> 6][1] = sv;
    part[tid >> 6][2] = sd; part[tid >> 6][3] = sa;
  }
  __syncthreads();
  if (tid == 0) {
    float sc[4];
    for (int k = 0; k < 4; ++k)
      sc[k] = (part[0][k] + part[1][k] + part[2][k] + part[3][k]) * (1.f / 36864.f);
    float logits[4];
    for (int k = 0; k < 4; ++k) logits[k] = b2[k];
    for (int j = 0; j < 32; ++j) {
      float hj = b1[j];
      for (int i = 0; i < 4; ++i) hj += sc[i] * w1[j * 4 + i];
      hj = fmaxf(hj, 0.f);
      for (int k = 0; k < 4; ++k) logits[k] += hj * w2[k * 32 + j];
    }
    int idx = 0;
    float best = logits[0];
    for (int k = 1; k < 4; ++k)
      if (logits[k] > best) { best = logits[k]; idx = k; }
    flag[b] = (idx == 1) ? 1 : 0;
  }
}

// --------------------------- out-proj GEMM ---------------------------------
__global__ __launch_bounds__(256) void k_gemm(const unsigned short* __restrict__ A,
                                              const unsigned short* __restrict__ Bw,
                                              const float* __restrict__ bias,
                                              const float* __restrict__ resid,
                                              float* __restrict__ out,
                                              int K, int N) {
  __shared__ unsigned short Al[128][40];
  __shared__ unsigned short Bl[128][40];
  const int tid = threadIdx.x;
  const long m0 = (long)blockIdx.x * 128;
  const int n0 = blockIdx.y * 128;
  const int rA = tid >> 2;
  const int cp = (tid & 3) * 8;

  const unsigned short* a0p = A + (m0 + rA) * K + cp;
  const unsigned short* a1p = A + (m0 + rA + 64) * K + cp;
  const unsigned short* b0p = Bw + (long)(n0 + rA) * K + cp;
  const unsigned short* b1p = Bw + (long)(n0 + rA + 64) * K + cp;

  const int wv = tid >> 6, lane = tid & 63;
  const int wm = (wv >> 1) * 64, wn = (wv & 1) * 64;
  const int fr = lane & 15, fq = lane >> 4;

  const f32x4 zero4 = {0.f, 0.f, 0.f, 0.f};
  f32x4 acc[4][4];
#pragma unroll
  for (int i = 0; i < 4; ++i)
#pragma unroll
    for (int j = 0; j < 4; ++j) acc[i][j] = zero4;

  for (int k0 = 0; k0 < K; k0 += 32) {
    half8 va0 = *(const half8*)(a0p + k0);
    half8 va1 = *(const half8*)(a1p + k0);
    half8 vb0 = *(const half8*)(b0p + k0);
    half8 vb1 = *(const half8*)(b1p + k0);
    __syncthreads();
    *(half8*)&Al[rA][cp] = va0;
    *(half8*)&Al[rA + 64][cp] = va1;
    *(half8*)&Bl[rA][cp] = vb0;
    *(half8*)&Bl[rA + 64][cp] = vb1;
    __syncthreads();
    half8 af[4], bf[4];
#pragma unroll
    for (int i = 0; i < 4; ++i) af[i] = *(const half8*)&Al[wm + i * 16 + fr][fq * 8];
#pragma unroll
    for (int j = 0; j < 4; ++j) bf[j] = *(const half8*)&Bl[wn + j * 16 + fr][fq * 8];
#pragma unroll
    for (int i = 0; i < 4; ++i)
#pragma unroll
      for (int j = 0; j < 4; ++j)
        acc[i][j] = __builtin_amdgcn_mfma_f32_16x16x32_f16(af[i], bf[j], acc[i][j], 0, 0, 0);
  }

#pragma unroll
  for (int j = 0; j < 4; ++j) {
    const int col = n0 + wn + j * 16 + fr;
    const float bv = bias[col];
#pragma unroll
    for (int i = 0; i < 4; ++i) {
      const long mbase = m0 + wm + i * 16 + fq * 4;
#pragma unroll
      for (int r = 0; r < 4; ++r) {
        const long m = mbase + r;
        out[m * N + col] = acc[i][j][r] + bv + resid[m * N + col];
      }
    }
  }
}

// ------------------------------- GRU scan v9 --------------------------------
// One WG per (batch, direction): 32 WGs, 768 threads (12 waves, 3/SIMD).
// Thread t = (g, u): g = t>>8 in {r,z,n}, u = t&255. Thread owns whh row
// g*256+u as 32 uint4 (128 packed-f16x2 VGPRs), reloaded per chunk via a
// laundered base pointer (no per-element pins -- backend rejects tied
// indirect operands). Per step: gh = dot2(row, h), h broadcast from LDS;
// g=1,2 deposit terms in LDS; g=0 does gate math, writes h + y. Chunk-GEMM
// (input-proj) runs on the otherwise-idle MFMA pipe. Two barriers/step.
__global__ __launch_bounds__(768, 3) void k_scan(
    const unsigned short* __restrict__ xn,
    const unsigned short* __restrict__ wcomb,
    const float* __restrict__ badj,
    const unsigned short* __restrict__ whh16,
    const float* __restrict__ bhhf,
    const float* __restrict__ bhhb,
    const int* __restrict__ flag,
    unsigned short* __restrict__ ycat) {
  const int dir = blockIdx.x & 1;
  const int b = blockIdx.x >> 1;
  const unsigned short* whh = whh16 + (long)dir * (768 * 256);
  const float* bhh = dir ? bhhb : bhhf;
  const unsigned short* wcd = wcomb + (long)dir * (768 * 256);
  const float* bcd = badj + dir * 768;
  const int tid = threadIdx.x;
  const int g = tid >> 8;         // gate 0..2
  const int u = tid & 255;        // unit
  const int wv = tid >> 6;        // wave 0..11
  const int lane = tid & 63;
  const int fr = lane & 15;
  const int fq = lane >> 4;
  const int fb = flag[b];

  __shared__ unsigned short xplds[CH][768];   // 48 KiB
  __shared__ unsigned short ylds[CH][256];    // 16 KiB
  __shared__ uint4 hl4[2][32];                // h double-buffer (256 f16 each)
  __shared__ float ghlds[512];                // z and n exchange

  float Bnh = 0.f;
  if (g == 2) Bnh = bhh[512 + u];
  float hreg = 0.f;
  if (tid < 128) ((unsigned*)hl4[0])[tid] = 0;

  const long xnb = (long)b * 4096;
  unsigned short* yb = ycat + (long)b * (L_ * 512) + dir * 256;

  const f32x4 zero4 = {0.f, 0.f, 0.f, 0.f};
  int pb = 0;  // current h buffer

  for (int c = 0; c < NCH; ++c) {
    const int cc = dir ? (NCH - 1 - c) : c;
    const int t0 = cc * CH;

    // ---- flush previous chunk's y from LDS to global (skip first) ----
    if (c > 0) {
      const int pt0 = (dir ? (NCH - c) : (c - 1)) * CH;
#pragma unroll
      for (int k = 0; k < 2; ++k) {
        const int idx = tid + 768 * k;
        if (idx < 1024) {
          const int tsx = idx >> 5;
          const int cl = (idx & 31) * 8;
          half8 v = *(const half8*)&ylds[tsx][cl];
          *(half8*)(yb + (long)(pt0 + tsx) * 512 + cl) = v;
        }
      }
    }

    // ---- chunk GEMM (MFMA pipe): xplds = seq[t0..t0+31] @ wcd.T + badj ----
    {
      const unsigned short* arow0;
      const unsigned short* arow1;
      {
        int t = t0 + fr;
        int p = fb ? (((t & 63) << 6) | (t >> 6)) : t;
        arow0 = xn + (xnb + p) * 256 + fq * 8;
        t = t0 + 16 + fr;
        p = fb ? (((t & 63) << 6) | (t >> 6)) : t;
        arow1 = xn + (xnb + p) * 256 + fq * 8;
      }
      f32x4 acc0[4], acc1[4];
#pragma unroll
      for (int i = 0; i < 4; ++i) { acc0[i] = zero4; acc1[i] = zero4; }
#pragma unroll
      for (int s = 0; s < 8; ++s) {
        half8 a0v = *(const half8*)(arow0 + s * 32);
        half8 a1v = *(const half8*)(arow1 + s * 32);
#pragma unroll
        for (int i = 0; i < 4; ++i) {
          const int n = (wv * 4 + i) * 16 + fr;
          half8 bfr = *(const half8*)(wcd + (long)n * 256 + s * 32 + fq * 8);
          acc0[i] = __builtin_amdgcn_mfma_f32_16x16x32_f16(a0v, bfr, acc0[i], 0, 0, 0);
          acc1[i] = __builtin_amdgcn_mfma_f32_16x16x32_f16(a1v, bfr, acc1[i], 0, 0, 0);
        }
      }
#pragma unroll
      for (int i = 0; i < 4; ++i) {
        const int n = (wv * 4 + i) * 16 + fr;
        const float bv = bcd[n];
#pragma unroll
        for (int r = 0; r < 4; ++r) {
          xplds[fq * 4 + r][n] = f2h(acc0[i][r] + bv);
          xplds[16 + fq * 4 + r][n] = f2h(acc1[i][r] + bv);
        }
      }
    }
    __syncthreads();  // xplds ready; h buffer init visible; ylds flushed

    // ---- reload this thread's whh row (laundered base pointer) ----
    uint4 wq[32];
    {
      const unsigned short* wp = whh + (long)tid * 256;
      asm volatile("" : "+v"(wp));
#pragma unroll
      for (int i = 0; i < 32; ++i) wq[i] = *(const uint4*)(wp + i * 8);
    }

    // ---- sequential GRU steps (VALU dot2 matvec) ----
    for (int lt = 0; lt < CH; ++lt) {
      const int ts = dir ? (CH - 1 - lt) : lt;
      const uint4* hp = hl4[pb];
      float a0 = 0.f, a1 = 0.f, a2 = 0.f, a3 = 0.f;
#pragma unroll
      for (int i = 0; i < 32; ++i) {
        uint4 hv = hp[i];  // same addr across lanes -> LDS broadcast
        a0 = dot2(wq[i].x, hv.x, a0);
        a1 = dot2(wq[i].y, hv.y, a1);
        a2 = dot2(wq[i].z, hv.z, a2);
        a3 = dot2(wq[i].w, hv.w, a3);
      }
      const float gh = (a0 + a1) + (a2 + a3);
      if (g == 1) ghlds[u] = h2f(xplds[ts][tid]) + gh;          // xz + ghz
      else if (g == 2) ghlds[256 + u] = gh + Bnh;               // ghn + bhh_n
      __syncthreads();
      if (g == 0) {
        const float r = sigm(h2f(xplds[ts][u]) + gh);
        const float z = sigm(ghlds[u]);
        const float n = tanhf_(h2f(xplds[ts][512 + u]) + r * ghlds[256 + u]);
        hreg = n + z * (hreg - n);
        const unsigned short hb = f2h(hreg);
        ((unsigned short*)hl4[pb ^ 1])[u] = hb;
        ylds[ts][u] = hb;
      }
      pb ^= 1;
      __syncthreads();
    }
  }
  // final chunk's y flush
  {
    const int pt0 = (dir ? 0 : (NCH - 1)) * CH;
#pragma unroll
    for (int k = 0; k < 2; ++k) {
      const int idx = tid + 768 * k;
      if (idx < 1024) {
        const int tsx = idx >> 5;
        const int cl = (idx & 31) * 8;
        half8 v = *(const half8*)&ylds[tsx][cl];
        *(half8*)(yb + (long)(pt0 + tsx) * 512 + cl) = v;
      }
    }
  }
}

// ------------------------------- launcher ----------------------------------
extern "C" void kernel_launch(void* const* d_in, const int* in_sizes, int n_in,
                              void* d_out, int out_size, void* d_ws, size_t ws_size,
                              hipStream_t stream) {
  (void)in_sizes; (void)n_in; (void)out_size; (void)ws_size;
  const float* x     = (const float*)d_in[0];
  const float* lng   = (const float*)d_in[1];
  const float* lnb   = (const float*)d_in[2];
  const float* w1    = (const float*)d_in[3];
  const float* b1    = (const float*)d_in[4];
  const float* w2    = (const float*)d_in[5];
  const float* b2    = (const float*)d_in[6];
  const float* in_w  = (const float*)d_in[7];
  const float* in_b  = (const float*)d_in[8];
  const float* wih_f = (const float*)d_in[9];
  const float* whh_f = (const float*)d_in[10];
  const float* bih_f = (const float*)d_in[11];
  const float* bhh_f = (const float*)d_in[12];
  const float* wih_b = (const float*)d_in[13];
  const float* whh_b = (const float*)d_in[14];
  const float* bih_b = (const float*)d_in[15];
  const float* bhh_b = (const float*)d_in[16];
  const float* out_w = (const float*)d_in[17];
  const float* out_b = (const float*)d_in[18];

  char* ws = (char*)d_ws;
  unsigned short* xn     = (unsigned short*)(ws + 0);
  float*          gray   = (float*)(ws + 33554432);
  int*            flag   = (int*)(ws + 33816576);
  unsigned short* whh16  = (unsigned short*)(ws + 33816832);
  unsigned short* outw16 = (unsigned short*)(ws + 34603264);
  unsigned short* wcomb  = (unsigned short*)(ws + 34865408);
  float*          badj   = (float*)(ws + 35651840);
  unsigned short* ycat   = (unsigned short*)(ws + 35658240);

  k_f2h<<<768, 256, 0, stream>>>(whh_f, whh16, 196608);
  k_f2h<<<768, 256, 0, stream>>>(whh_b, whh16 + 196608, 196608);
  k_f2h<<<512, 256, 0, stream>>>(out_w, outw16, 131072);
  k_wcomb<<<1536, 256, 0, stream>>>(wih_f, wih_b, in_w, wcomb);
  k_bcomb<<<6, 256, 0, stream>>>(wih_f, wih_b, in_b, bih_f, bih_b,
                                 bhh_f, bhh_b, badj);
  k_ln<<<16384, 256, 0, stream>>>(x, lng, lnb, xn, gray);
  k_sel<<<16, 256, 0, stream>>>(gray, w1, b1, w2, b2, flag);
  k_scan<<<32, 768, 0, stream>>>(xn, wcomb, badj, whh16,
                                 bhh_f, bhh_b, flag, ycat);
  dim3 gout(512, 2);
  k_gemm<<<gout, 256, 0, stream>>>(ycat, outw16, out_b, x, (float*)d_out, 512, 256);
}

// Round 11
// 8288.229 us; speedup vs baseline: 1.0059x; 1.0059x over previous
//
#include <hip/hip_runtime.h>

// ---------------------------------------------------------------------------
// FastCASSBlock: LN -> gradient-direction selector -> biGRU (input-proj fused
// into scan chunks) -> out_proj + residual.
// v11 = v10 with the asm-operand type fix: weight registers are ext_vector
// uvec4 (register tuples -- tied "+v" supported), not HIP's struct uint4
// (passed indirectly -> "tied indirect register inputs" error). 32 named
// uvec4 loaded per chunk, pinned by volatile asm => genuinely resident;
// recurrence matvec on VALU v_dot2_f32_f16; chunk input-proj GEMM on MFMA.
// Workspace layout (bytes), total ~98 MiB:
//   xn    f16 [65536,256]  @ 0           (33554432)
//   gray  f32 [65536]      @ 33554432    (262144)
//   flag  i32 [16]         @ 33816576    (256)
//   whh16 f16 [2][768,256] @ 33816832    (786432)
//   out_w f16 [256,512]    @ 34603264    (262144)
//   wcomb f16 [1536,256]   @ 34865408    (786432)
//   badj  f32 [1536]       @ 35651840    (6144)
//   ycat  f16 [65536,512]  @ 35658240    (67108864)
// ---------------------------------------------------------------------------

#define L_   4096
#define CH   32     // scan chunk length (steps)
#define NCH  128    // L_/CH

typedef __attribute__((ext_vector_type(8))) _Float16 half8;
typedef __attribute__((ext_vector_type(2))) _Float16 half2v;
typedef __attribute__((ext_vector_type(4))) float f32x4;
typedef __attribute__((ext_vector_type(4))) unsigned uvec4;

__device__ __forceinline__ unsigned short f2h(float f) {
  _Float16 h = (_Float16)f;
  return __builtin_bit_cast(unsigned short, h);
}
__device__ __forceinline__ float h2f(unsigned short u) {
  return (float)__builtin_bit_cast(_Float16, u);
}
__device__ __forceinline__ float sigm(float x) {
  return __builtin_amdgcn_rcpf(1.f + __expf(-x));
}
__device__ __forceinline__ float tanhf_(float x) {
  return 1.f - 2.f * __builtin_amdgcn_rcpf(1.f + __expf(2.f * x));
}
__device__ __forceinline__ float dot2(unsigned w, unsigned h, float c) {
  return __builtin_amdgcn_fdot2(__builtin_bit_cast(half2v, w),
                                __builtin_bit_cast(half2v, h), c, false);
}

// --------------------------- f32 -> f16 convert ----------------------------
__global__ __launch_bounds__(256) void k_f2h(const float* __restrict__ in,
                                             unsigned short* __restrict__ out,
                                             int n) {
  int i = blockIdx.x * 256 + threadIdx.x;
  if (i < n) out[i] = f2h(in[i]);
}

// ------------------- wcomb[n,c] = sum_j wih[n,j]*in_w[j,c] -----------------
__global__ __launch_bounds__(256) void k_wcomb(const float* __restrict__ wih_f,
                                               const float* __restrict__ wih_b,
                                               const float* __restrict__ in_w,
                                               unsigned short* __restrict__ wcomb) {
  const int n = blockIdx.x;  // 0..1535
  const float* wrow = (n < 768) ? (wih_f + (long)n * 512)
                                : (wih_b + (long)(n - 768) * 512);
  const int k = threadIdx.x;  // 0..255
  float acc = 0.f;
  for (int j = 0; j < 512; ++j) acc += wrow[j] * in_w[j * 256 + k];
  wcomb[(long)n * 256 + k] = f2h(acc);
}

// -- badj[n] = bih[n] + sum_j wih[n,j]*in_b[j] (+ bhh[n] for r/z slots) ------
__global__ __launch_bounds__(256) void k_bcomb(const float* __restrict__ wih_f,
                                               const float* __restrict__ wih_b,
                                               const float* __restrict__ in_b,
                                               const float* __restrict__ bih_f,
                                               const float* __restrict__ bih_b,
                                               const float* __restrict__ bhh_f,
                                               const float* __restrict__ bhh_b,
                                               float* __restrict__ badj) {
  int n = blockIdx.x * 256 + threadIdx.x;
  if (n >= 1536) return;
  const int dir = n >= 768;
  const int g = dir ? (n - 768) : n;
  const float* wrow = (dir ? wih_b : wih_f) + (long)g * 512;
  float acc = (dir ? bih_b : bih_f)[g];
  for (int j = 0; j < 512; ++j) acc += wrow[j] * in_b[j];
  if (g < 512) acc += (dir ? bhh_b : bhh_f)[g];  // fold bhh for r,z gates
  badj[n] = acc;
}

// --------------------------- LayerNorm + gray ------------------------------
__global__ __launch_bounds__(256) void k_ln(const float* __restrict__ x,
                                            const float* __restrict__ gamma,
                                            const float* __restrict__ beta,
                                            unsigned short* __restrict__ xn,
                                            float* __restrict__ gray) {
  const int lane = threadIdx.x & 63;
  const long pix = (long)blockIdx.x * 4 + (threadIdx.x >> 6);
  const float4 v = *(const float4*)(x + pix * 256 + lane * 4);
  float s = v.x + v.y + v.z + v.w;
  float s2 = v.x * v.x + v.y * v.y + v.z * v.z + v.w * v.w;
#pragma unroll
  for (int off = 32; off > 0; off >>= 1) {
    s += __shfl_xor(s, off, 64);
    s2 += __shfl_xor(s2, off, 64);
  }
  const float mu = s * (1.f / 256.f);
  const float var = fmaxf(s2 * (1.f / 256.f) - mu * mu, 0.f);
  const float rstd = rsqrtf(var + 1e-5f);
  const float4 gm = *(const float4*)(gamma + lane * 4);
  const float4 bt = *(const float4*)(beta + lane * 4);
  float o0 = (v.x - mu) * rstd * gm.x + bt.x;
  float o1 = (v.y - mu) * rstd * gm.y + bt.y;
  float o2 = (v.z - mu) * rstd * gm.z + bt.z;
  float o3 = (v.w - mu) * rstd * gm.w + bt.w;
  ushort4 o;
  o.x = f2h(o0); o.y = f2h(o1); o.z = f2h(o2); o.w = f2h(o3);
  *(ushort4*)(xn + pix * 256 + lane * 4) = o;
  float gs = o0 + o1 + o2 + o3;
#pragma unroll
  for (int off = 32; off > 0; off >>= 1) gs += __shfl_xor(gs, off, 64);
  if (lane == 0) gray[pix] = gs * (1.f / 256.f);
}

// --------------------- gradient-direction selector -------------------------
__device__ __forceinline__ int refl64(int m) {
  return m < 0 ? -m : (m > 63 ? 126 - m : m);
}

__global__ __launch_bounds__(256) void k_sel(const float* __restrict__ gray,
                                             const float* __restrict__ w1,
                                             const float* __restrict__ b1,
                                             const float* __restrict__ w2,
                                             const float* __restrict__ b2,
                                             int* __restrict__ flag) {
  __shared__ float g[64][65];
  __shared__ float part[4][4];
  const int b = blockIdx.x;
  const int tid = threadIdx.x;
  for (int r = 0; r < 16; ++r) {
    int p = tid + 256 * r;
    g[p >> 6][p & 63] = gray[(long)b * 4096 + p];
  }
  __syncthreads();
  const float S = 66.f / 64.f;
  float sh = 0.f, sv = 0.f, sd = 0.f, sa = 0.f;
  for (int rr = 0; rr < 16; ++rr) {
    int p = tid + 256 * rr;
    int h = p >> 6, w = p & 63;
    float srci = (h + 0.5f) * S - 0.5f;
    int i0 = (int)srci;
    float ai = srci - (float)i0;
    int i1 = i0 + 1; if (i1 > 65) i1 = 65;
    int r0 = refl64(i0 - 1), r1 = refl64(i1 - 1);
    int wl = w ? (w - 1) : 1;
    int wr2 = (w == 63) ? 62 : (w + 1);
    float GH0 = fabsf(g[r0][wr2] - g[r0][wl]);
    float GH1 = fabsf(g[r1][wr2] - g[r1][wl]);
    float ghr = GH0 + ai * (GH1 - GH0);
    float srcj = (w + 0.5f) * S - 0.5f;
    int j0 = (int)srcj;
    float aj = srcj - (float)j0;
    int j1 = j0 + 1; if (j1 > 65) j1 = 65;
    int c0 = refl64(j0 - 1), c1 = refl64(j1 - 1);
    int hu = h ? (h - 1) : 1;
    int hd = (h == 63) ? 62 : (h + 1);
    float GV0 = fabsf(g[hd][c0] - g[hu][c0]);
    float GV1 = fabsf(g[hd][c1] - g[hu][c1]);
    float gvr = GV0 + aj * (GV1 - GV0);
    float wt = ((h == 0 || h == 63) ? 2.f : 3.f) *
               ((w == 0 || w == 63) ? 2.f : 3.f);
    sh += wt * ghr;
    sv += wt * gvr;
    sd += wt * 0.5f * (ghr + gvr);
    sa += wt * fabsf(ghr - gvr);
  }
#pragma unroll
  for (int off = 32; off > 0; off >>= 1) {
    sh += __shfl_xor(sh, off, 64);
    sv += __shfl_xor(sv, off, 64);
    sd += __shfl_xor(sd, off, 64);
    sa += __shfl_xor(sa, off, 64);
  }
  if ((tid & 63) == 0) {
    part[tid >> 6][0] = sh; part[tid >> 6][1] = sv;
    part[tid >> 6][2] = sd; part[tid >> 6][3] = sa;
  }
  __syncthreads();
  if (tid == 0) {
    float sc[4];
    for (int k = 0; k < 4; ++k)
      sc[k] = (part[0][k] + part[1][k] + part[2][k] + part[3][k]) * (1.f / 36864.f);
    float logits[4];
    for (int k = 0; k < 4; ++k) logits[k] = b2[k];
    for (int j = 0; j < 32; ++j) {
      float hj = b1[j];
      for (int i = 0; i < 4; ++i) hj += sc[i] * w1[j * 4 + i];
      hj = fmaxf(hj, 0.f);
      for (int k = 0; k < 4; ++k) logits[k] += hj * w2[k * 32 + j];
    }
    int idx = 0;
    float best = logits[0];
    for (int k = 1; k < 4; ++k)
      if (logits[k] > best) { best = logits[k]; idx = k; }
    flag[b] = (idx == 1) ? 1 : 0;
  }
}

// --------------------------- out-proj GEMM ---------------------------------
__global__ __launch_bounds__(256) void k_gemm(const unsigned short* __restrict__ A,
                                              const unsigned short* __restrict__ Bw,
                                              const float* __restrict__ bias,
                                              const float* __restrict__ resid,
                                              float* __restrict__ out,
                                              int K, int N) {
  __shared__ unsigned short Al[128][40];
  __shared__ unsigned short Bl[128][40];
  const int tid = threadIdx.x;
  const long m0 = (long)blockIdx.x * 128;
  const int n0 = blockIdx.y * 128;
  const int rA = tid >> 2;
  const int cp = (tid & 3) * 8;

  const unsigned short* a0p = A + (m0 + rA) * K + cp;
  const unsigned short* a1p = A + (m0 + rA + 64) * K + cp;
  const unsigned short* b0p = Bw + (long)(n0 + rA) * K + cp;
  const unsigned short* b1p = Bw + (long)(n0 + rA + 64) * K + cp;

  const int wv = tid >> 6, lane = tid & 63;
  const int wm = (wv >> 1) * 64, wn = (wv & 1) * 64;
  const int fr = lane & 15, fq = lane >> 4;

  const f32x4 zero4 = {0.f, 0.f, 0.f, 0.f};
  f32x4 acc[4][4];
#pragma unroll
  for (int i = 0; i < 4; ++i)
#pragma unroll
    for (int j = 0; j < 4; ++j) acc[i][j] = zero4;

  for (int k0 = 0; k0 < K; k0 += 32) {
    half8 va0 = *(const half8*)(a0p + k0);
    half8 va1 = *(const half8*)(a1p + k0);
    half8 vb0 = *(const half8*)(b0p + k0);
    half8 vb1 = *(const half8*)(b1p + k0);
    __syncthreads();
    *(half8*)&Al[rA][cp] = va0;
    *(half8*)&Al[rA + 64][cp] = va1;
    *(half8*)&Bl[rA][cp] = vb0;
    *(half8*)&Bl[rA + 64][cp] = vb1;
    __syncthreads();
    half8 af[4], bf[4];
#pragma unroll
    for (int i = 0; i < 4; ++i) af[i] = *(const half8*)&Al[wm + i * 16 + fr][fq * 8];
#pragma unroll
    for (int j = 0; j < 4; ++j) bf[j] = *(const half8*)&Bl[wn + j * 16 + fr][fq * 8];
#pragma unroll
    for (int i = 0; i < 4; ++i)
#pragma unroll
      for (int j = 0; j < 4; ++j)
        acc[i][j] = __builtin_amdgcn_mfma_f32_16x16x32_f16(af[i], bf[j], acc[i][j], 0, 0, 0);
  }

#pragma unroll
  for (int j = 0; j < 4; ++j) {
    const int col = n0 + wn + j * 16 + fr;
    const float bv = bias[col];
#pragma unroll
    for (int i = 0; i < 4; ++i) {
      const long mbase = m0 + wm + i * 16 + fq * 4;
#pragma unroll
      for (int r = 0; r < 4; ++r) {
        const long m = mbase + r;
        out[m * N + col] = acc[i][j][r] + bv + resid[m * N + col];
      }
    }
  }
}

// ------------------------------- GRU scan v11 -------------------------------
// One WG per (batch, direction): 32 WGs, 768 threads (12 waves, 3/SIMD).
// Thread t = (g, u): g = t>>8 in {r,z,n}, u = t&255. Thread owns whh row
// g*256+u as 32 NAMED ext_vector uvec4 (128 VGPRs), loaded per chunk and
// pinned by volatile asm (ext_vector = register tuple, tied "+v" supported;
// HIP's struct uint4 is passed indirectly and rejected). Asm-defined values
// cannot be rematerialized -> true residency.
// Per step: gh = dot2(row, h), h broadcast via same-address LDS uvec4 reads;
// g=1,2 deposit terms in LDS; g=0 does gate math, writes h + y.
__global__ __launch_bounds__(768, 3) void k_scan(
    const unsigned short* __restrict__ xn,
    const unsigned short* __restrict__ wcomb,
    const float* __restrict__ badj,
    const unsigned short* __restrict__ whh16,
    const float* __restrict__ bhhf,
    const float* __restrict__ bhhb,
    const int* __restrict__ flag,
    unsigned short* __restrict__ ycat) {
  const int dir = blockIdx.x & 1;
  const int b = blockIdx.x >> 1;
  const unsigned short* whh = whh16 + (long)dir * (768 * 256);
  const float* bhh = dir ? bhhb : bhhf;
  const unsigned short* wcd = wcomb + (long)dir * (768 * 256);
  const float* bcd = badj + dir * 768;
  const int tid = threadIdx.x;
  const int g = tid >> 8;         // gate 0..2
  const int u = tid & 255;        // unit
  const int wv = tid >> 6;        // wave 0..11
  const int lane = tid & 63;
  const int fr = lane & 15;
  const int fq = lane >> 4;
  const int fb = flag[b];

  __shared__ unsigned short xplds[CH][768];   // 48 KiB
  __shared__ unsigned short ylds[CH][256];    // 16 KiB
  __shared__ uvec4 hl4[2][32];                // h double-buffer (256 f16 each)
  __shared__ float ghlds[512];                // z and n exchange

  float Bnh = 0.f;
  if (g == 2) Bnh = bhh[512 + u];
  float hreg = 0.f;
  if (tid < 128) ((unsigned*)hl4[0])[tid] = 0;

  const long xnb = (long)b * 4096;
  unsigned short* yb = ycat + (long)b * (L_ * 512) + dir * 256;

  const f32x4 zero4 = {0.f, 0.f, 0.f, 0.f};
  int pb = 0;  // current h buffer

  for (int c = 0; c < NCH; ++c) {
    const int cc = dir ? (NCH - 1 - c) : c;
    const int t0 = cc * CH;

    // ---- flush previous chunk's y from LDS to global (skip first) ----
    if (c > 0) {
      const int pt0 = (dir ? (NCH - c) : (c - 1)) * CH;
#pragma unroll
      for (int k = 0; k < 2; ++k) {
        const int idx = tid + 768 * k;
        if (idx < 1024) {
          const int tsx = idx >> 5;
          const int cl = (idx & 31) * 8;
          half8 v = *(const half8*)&ylds[tsx][cl];
          *(half8*)(yb + (long)(pt0 + tsx) * 512 + cl) = v;
        }
      }
    }

    // ---- chunk GEMM (MFMA pipe): xplds = seq[t0..t0+31] @ wcd.T + badj ----
    {
      const unsigned short* arow0;
      const unsigned short* arow1;
      {
        int t = t0 + fr;
        int p = fb ? (((t & 63) << 6) | (t >> 6)) : t;
        arow0 = xn + (xnb + p) * 256 + fq * 8;
        t = t0 + 16 + fr;
        p = fb ? (((t & 63) << 6) | (t >> 6)) : t;
        arow1 = xn + (xnb + p) * 256 + fq * 8;
      }
      f32x4 acc0[4], acc1[4];
#pragma unroll
      for (int i = 0; i < 4; ++i) { acc0[i] = zero4; acc1[i] = zero4; }
#pragma unroll
      for (int s = 0; s < 8; ++s) {
        half8 a0v = *(const half8*)(arow0 + s * 32);
        half8 a1v = *(const half8*)(arow1 + s * 32);
#pragma unroll
        for (int i = 0; i < 4; ++i) {
          const int n = (wv * 4 + i) * 16 + fr;
          half8 bfr = *(const half8*)(wcd + (long)n * 256 + s * 32 + fq * 8);
          acc0[i] = __builtin_amdgcn_mfma_f32_16x16x32_f16(a0v, bfr, acc0[i], 0, 0, 0);
          acc1[i] = __builtin_amdgcn_mfma_f32_16x16x32_f16(a1v, bfr, acc1[i], 0, 0, 0);
        }
      }
#pragma unroll
      for (int i = 0; i < 4; ++i) {
        const int n = (wv * 4 + i) * 16 + fr;
        const float bv = bcd[n];
#pragma unroll
        for (int r = 0; r < 4; ++r) {
          xplds[fq * 4 + r][n] = f2h(acc0[i][r] + bv);
          xplds[16 + fq * 4 + r][n] = f2h(acc1[i][r] + bv);
        }
      }
    }
    __syncthreads();  // xplds ready; h buffer init visible; ylds flushed

    // ---- load whh row into 32 NAMED ext-vector regs, pin with asm ----
    const uvec4* wp = (const uvec4*)(whh + (long)tid * 256);
    uvec4 w00 = wp[0],  w01 = wp[1],  w02 = wp[2],  w03 = wp[3];
    uvec4 w04 = wp[4],  w05 = wp[5],  w06 = wp[6],  w07 = wp[7];
    uvec4 w08 = wp[8],  w09 = wp[9],  w10 = wp[10], w11 = wp[11];
    uvec4 w12 = wp[12], w13 = wp[13], w14 = wp[14], w15 = wp[15];
    uvec4 w16 = wp[16], w17 = wp[17], w18 = wp[18], w19 = wp[19];
    uvec4 w20 = wp[20], w21 = wp[21], w22 = wp[22], w23 = wp[23];
    uvec4 w24 = wp[24], w25 = wp[25], w26 = wp[26], w27 = wp[27];
    uvec4 w28 = wp[28], w29 = wp[29], w30 = wp[30], w31 = wp[31];
    asm volatile("" : "+v"(w00), "+v"(w01), "+v"(w02), "+v"(w03),
                      "+v"(w04), "+v"(w05), "+v"(w06), "+v"(w07));
    asm volatile("" : "+v"(w08), "+v"(w09), "+v"(w10), "+v"(w11),
                      "+v"(w12), "+v"(w13), "+v"(w14), "+v"(w15));
    asm volatile("" : "+v"(w16), "+v"(w17), "+v"(w18), "+v"(w19),
                      "+v"(w20), "+v"(w21), "+v"(w22), "+v"(w23));
    asm volatile("" : "+v"(w24), "+v"(w25), "+v"(w26), "+v"(w27),
                      "+v"(w28), "+v"(w29), "+v"(w30), "+v"(w31));

    // ---- sequential GRU steps (VALU dot2 matvec) ----
    for (int lt = 0; lt < CH; ++lt) {
      const int ts = dir ? (CH - 1 - lt) : lt;
      const uvec4* hp = hl4[pb];
      float a0 = 0.f, a1 = 0.f, a2 = 0.f, a3 = 0.f;
#define DOT4(I, W)                               \
      {                                          \
        uvec4 hv = hp[I];                        \
        a0 = dot2(W.x, hv.x, a0);                \
        a1 = dot2(W.y, hv.y, a1);                \
        a2 = dot2(W.z, hv.z, a2);                \
        a3 = dot2(W.w, hv.w, a3);                \
      }
      DOT4(0, w00)  DOT4(1, w01)  DOT4(2, w02)  DOT4(3, w03)
      DOT4(4, w04)  DOT4(5, w05)  DOT4(6, w06)  DOT4(7, w07)
      DOT4(8, w08)  DOT4(9, w09)  DOT4(10, w10) DOT4(11, w11)
      DOT4(12, w12) DOT4(13, w13) DOT4(14, w14) DOT4(15, w15)
      DOT4(16, w16) DOT4(17, w17) DOT4(18, w18) DOT4(19, w19)
      DOT4(20, w20) DOT4(21, w21) DOT4(22, w22) DOT4(23, w23)
      DOT4(24, w24) DOT4(25, w25) DOT4(26, w26) DOT4(27, w27)
      DOT4(28, w28) DOT4(29, w29) DOT4(30, w30) DOT4(31, w31)
#undef DOT4
      const float gh = (a0 + a1) + (a2 + a3);
      if (g == 1) ghlds[u] = h2f(xplds[ts][tid]) + gh;          // xz + ghz
      else if (g == 2) ghlds[256 + u] = gh + Bnh;               // ghn + bhh_n
      __syncthreads();
      if (g == 0) {
        const float r = sigm(h2f(xplds[ts][u]) + gh);
        const float z = sigm(ghlds[u]);
        const float n = tanhf_(h2f(xplds[ts][512 + u]) + r * ghlds[256 + u]);
        hreg = n + z * (hreg - n);
        const unsigned short hb = f2h(hreg);
        ((unsigned short*)hl4[pb ^ 1])[u] = hb;
        ylds[ts][u] = hb;
      }
      pb ^= 1;
      __syncthreads();
    }
  }
  // final chunk's y flush
  {
    const int pt0 = (dir ? 0 : (NCH - 1)) * CH;
#pragma unroll
    for (int k = 0; k < 2; ++k) {
      const int idx = tid + 768 * k;
      if (idx < 1024) {
        const int tsx = idx >> 5;
        const int cl = (idx & 31) * 8;
        half8 v = *(const half8*)&ylds[tsx][cl];
        *(half8*)(yb + (long)(pt0 + tsx) * 512 + cl) = v;
      }
    }
  }
}

// ------------------------------- launcher ----------------------------------
extern "C" void kernel_launch(void* const* d_in, const int* in_sizes, int n_in,
                              void* d_out, int out_size, void* d_ws, size_t ws_size,
                              hipStream_t stream) {
  (void)in_sizes; (void)n_in; (void)out_size; (void)ws_size;
  const float* x     = (const float*)d_in[0];
  const float* lng   = (const float*)d_in[1];
  const float* lnb   = (const float*)d_in[2];
  const float* w1    = (const float*)d_in[3];
  const float* b1    = (const float*)d_in[4];
  const float* w2    = (const float*)d_in[5];
  const float* b2    = (const float*)d_in[6];
  const float* in_w  = (const float*)d_in[7];
  const float* in_b  = (const float*)d_in[8];
  const float* wih_f = (const float*)d_in[9];
  const float* whh_f = (const float*)d_in[10];
  const float* bih_f = (const float*)d_in[11];
  const float* bhh_f = (const float*)d_in[12];
  const float* wih_b = (const float*)d_in[13];
  const float* whh_b = (const float*)d_in[14];
  const float* bih_b = (const float*)d_in[15];
  const float* bhh_b = (const float*)d_in[16];
  const float* out_w = (const float*)d_in[17];
  const float* out_b = (const float*)d_in[18];

  char* ws = (char*)d_ws;
  unsigned short* xn     = (unsigned short*)(ws + 0);
  float*          gray   = (float*)(ws + 33554432);
  int*            flag   = (int*)(ws + 33816576);
  unsigned short* whh16  = (unsigned short*)(ws + 33816832);
  unsigned short* outw16 = (unsigned short*)(ws + 34603264);
  unsigned short* wcomb  = (unsigned short*)(ws + 34865408);
  float*          badj   = (float*)(ws + 35651840);
  unsigned short* ycat   = (unsigned short*)(ws + 35658240);

  k_f2h<<<768, 256, 0, stream>>>(whh_f, whh16, 196608);
  k_f2h<<<768, 256, 0, stream>>>(whh_b, whh16 + 196608, 196608);
  k_f2h<<<512, 256, 0, stream>>>(out_w, outw16, 131072);
  k_wcomb<<<1536, 256, 0, stream>>>(wih_f, wih_b, in_w, wcomb);
  k_bcomb<<<6, 256, 0, stream>>>(wih_f, wih_b, in_b, bih_f, bih_b,
                                 bhh_f, bhh_b, badj);
  k_ln<<<16384, 256, 0, stream>>>(x, lng, lnb, xn, gray);
  k_sel<<<16, 256, 0, stream>>>(gray, w1, b1, w2, b2, flag);
  k_scan<<<32, 768, 0, stream>>>(xn, wcomb, badj, whh16,
                                 bhh_f, bhh_b, flag, ycat);
  dim3 gout(512, 2);
  k_gemm<<<gout, 256, 0, stream>>>(ycat, outw16, out_b, x, (float*)d_out, 512, 256);
}